// Round 4
// baseline (127.726 us; speedup 1.0000x reference)
//
#include <hip/hip_runtime.h>

#define BB 64
#define SS 512
#define HH 1024
#define SUP 100
#define KFS 5
#define NCLS 3
#define SEG 32            // pool s-segments
#define KSPLIT 8          // K-split for K2 GEMM partials
#define KB (HH / KSPLIT)  // 128
#define KC 32             // K per LDS chunk
#define ASLD 68           // padded LDS row
#define WKS 4             // W_cm m-split
#define WKB (HH / WKS)    // 256

#define POOL_BLKS (BB * SEG)   // 2048
#define WG_BLKS   256          // W_cm partial blocks (4 o-tiles x 16 h-tiles x 4 ksplit)

// ======================= K1: pool partials + W_cm + b_cm + flag reset =======================
__global__ void k1_pool_wgemm(const float* __restrict__ hs,
                              const float* __restrict__ W_con,
                              const float* __restrict__ W_met,
                              const float* __restrict__ b_met,
                              const float* __restrict__ b_con,
                              float* __restrict__ part,
                              float* __restrict__ pWcm,
                              float* __restrict__ b_cm,
                              unsigned int* __restrict__ flags) {
    int blk = blockIdx.x, t = threadIdx.x;

    if (blk < POOL_BLKS) {                       // ---- pooling partials (HBM-bound) ----
        int b = blk >> 5, seg = blk & (SEG - 1);
        const float4* src = (const float4*)(hs + (size_t)b * SS * HH);
        float4 acc = make_float4(0.f, 0.f, 0.f, 0.f);
        int s0 = seg * (SS / SEG);
#pragma unroll
        for (int s = s0; s < s0 + (SS / SEG); ++s) {
            float4 v = src[s * 256 + t];
            acc.x += v.x; acc.y += v.y; acc.z += v.z; acc.w += v.w;
        }
        ((float4*)part)[(seg * BB + b) * 256 + t] = acc;
        return;
    }

    if (blk < POOL_BLKS + WG_BLKS) {             // ---- W_cm[o,h] = sum_m W_con[o,m]*W_met[m,h], m-split 4 ----
        __shared__ __align__(16) float As[KC][ASLD];
        __shared__ __align__(16) float Bs[KC][ASLD];
        int id = blk - POOL_BLKS;
        int p    = id & 3;
        int tile = id >> 2;                      // 0..63
        int o0 = (tile & 3) * 64;
        int h0 = (tile >> 2) * 64;
        int m0 = p * WKB;
        int tm = t >> 4, tn = t & 15;
        int lr = t >> 2, lq = t & 3;             // A-stage: o-row, m-quad
        int mr = t >> 3, hq = t & 7;             // B-stage: m-row, h-quad
        float acc[4][4] = {};
        for (int kc = 0; kc < WKB; kc += KC) {
            int ma = m0 + kc;
            float4 a0 = *(const float4*)(W_con + (size_t)(o0 + lr) * HH + ma + lq * 4);
            float4 a1 = *(const float4*)(W_con + (size_t)(o0 + lr) * HH + ma + lq * 4 + 16);
            As[lq*4+0][lr] = a0.x; As[lq*4+1][lr] = a0.y; As[lq*4+2][lr] = a0.z; As[lq*4+3][lr] = a0.w;
            As[16+lq*4+0][lr] = a1.x; As[16+lq*4+1][lr] = a1.y; As[16+lq*4+2][lr] = a1.z; As[16+lq*4+3][lr] = a1.w;
            float4 w0 = *(const float4*)(W_met + (size_t)(ma + mr) * HH + h0 + hq * 4);
            float4 w1 = *(const float4*)(W_met + (size_t)(ma + mr) * HH + h0 + hq * 4 + 32);
            *(float4*)&Bs[mr][hq * 4]      = w0;
            *(float4*)&Bs[mr][hq * 4 + 32] = w1;
            __syncthreads();
#pragma unroll
            for (int k = 0; k < KC; ++k) {
                float4 a4 = *(const float4*)&As[k][tm * 4];
                float4 b4 = *(const float4*)&Bs[k][tn * 4];
                acc[0][0] += a4.x * b4.x; acc[0][1] += a4.x * b4.y;
                acc[0][2] += a4.x * b4.z; acc[0][3] += a4.x * b4.w;
                acc[1][0] += a4.y * b4.x; acc[1][1] += a4.y * b4.y;
                acc[1][2] += a4.y * b4.z; acc[1][3] += a4.y * b4.w;
                acc[2][0] += a4.z * b4.x; acc[2][1] += a4.z * b4.y;
                acc[2][2] += a4.z * b4.z; acc[2][3] += a4.z * b4.w;
                acc[3][0] += a4.w * b4.x; acc[3][1] += a4.w * b4.y;
                acc[3][2] += a4.w * b4.z; acc[3][3] += a4.w * b4.w;
            }
            __syncthreads();
        }
#pragma unroll
        for (int i = 0; i < 4; ++i)
            *(float4*)(pWcm + ((size_t)p * 256 + o0 + tm * 4 + i) * HH + h0 + tn * 4) =
                make_float4(acc[i][0], acc[i][1], acc[i][2], acc[i][3]);
        return;
    }

    // ---- last block: zero phase flags; b_cm[o] = dot(W_con[o,:], b_met) + b_con[o] ----
    if (t < 2) flags[t] = 0u;
    float s = b_con[t];
    const float4* wr  = (const float4*)(W_con + (size_t)t * HH);
    const float4* bm4 = (const float4*)b_met;
#pragma unroll 8
    for (int m = 0; m < HH / 4; ++m) {
        float4 w = wr[m], bm = bm4[m];
        s += w.x * bm.x + w.y * bm.y + w.z * bm.z + w.w * bm.w;
    }
    b_cm[t] = s;
}

// ---------------- 64x64 K-partial GEMM tile (A, W both row-major, K contiguous) ----------------
__device__ __forceinline__ void gemm64_partial(const float* __restrict__ A,
                                               const float* __restrict__ W,
                                               float* __restrict__ partOut, int N,
                                               int n0, int k0, int ks, int t,
                                               float (*As)[ASLD], float (*Bs)[ASLD]) {
    int tm = t >> 4, tn = t & 15;
    int lr = t >> 2, lq = t & 3;
    float acc[4][4] = {};
    for (int kc = 0; kc < KB; kc += KC) {
        int ka = k0 + kc + lq * 4;
        float4 a0 = *(const float4*)(A + (size_t)lr * HH + ka);
        float4 a1 = *(const float4*)(A + (size_t)lr * HH + ka + 16);
        float4 w0 = *(const float4*)(W + (size_t)(n0 + lr) * HH + ka);
        float4 w1 = *(const float4*)(W + (size_t)(n0 + lr) * HH + ka + 16);
        As[lq*4+0][lr] = a0.x; As[lq*4+1][lr] = a0.y; As[lq*4+2][lr] = a0.z; As[lq*4+3][lr] = a0.w;
        As[16+lq*4+0][lr] = a1.x; As[16+lq*4+1][lr] = a1.y; As[16+lq*4+2][lr] = a1.z; As[16+lq*4+3][lr] = a1.w;
        Bs[lq*4+0][lr] = w0.x; Bs[lq*4+1][lr] = w0.y; Bs[lq*4+2][lr] = w0.z; Bs[lq*4+3][lr] = w0.w;
        Bs[16+lq*4+0][lr] = w1.x; Bs[16+lq*4+1][lr] = w1.y; Bs[16+lq*4+2][lr] = w1.z; Bs[16+lq*4+3][lr] = w1.w;
        __syncthreads();
#pragma unroll
        for (int k = 0; k < KC; ++k) {
            float4 a4 = *(const float4*)&As[k][tm * 4];
            float4 b4 = *(const float4*)&Bs[k][tn * 4];
            acc[0][0] += a4.x * b4.x; acc[0][1] += a4.x * b4.y;
            acc[0][2] += a4.x * b4.z; acc[0][3] += a4.x * b4.w;
            acc[1][0] += a4.y * b4.x; acc[1][1] += a4.y * b4.y;
            acc[1][2] += a4.y * b4.z; acc[1][3] += a4.y * b4.w;
            acc[2][0] += a4.z * b4.x; acc[2][1] += a4.z * b4.y;
            acc[2][2] += a4.z * b4.z; acc[2][3] += a4.z * b4.w;
            acc[3][0] += a4.w * b4.x; acc[3][1] += a4.w * b4.y;
            acc[3][2] += a4.w * b4.z; acc[3][3] += a4.w * b4.w;
        }
        __syncthreads();
    }
#pragma unroll
    for (int i = 0; i < 4; ++i)
        *(float4*)(partOut + ((size_t)ks * 64 + tm * 4 + i) * N + n0 + tn * 4) =
            make_float4(acc[i][0], acc[i][1], acc[i][2], acc[i][3]);
}

// ======================= K2: reduce -> {fewshot | GEMM partials} -> combine =======================
// blocks 0..63: reduce pooled[b], publish (flag0); fewshot(b).
// blocks 64..127: wait flag0; sim/div/con K-partials; publish (flag1).
// blocks 128..135: wait flag1; combine partials + bias -> outputs.
__global__ void __launch_bounds__(256, 2)
k2_main(const float* __restrict__ part,
        const float* __restrict__ supF,
        const int* __restrict__ labels,
        const int* __restrict__ supL,
        const float* __restrict__ W_sim, const float* __restrict__ b_sim,
        const float* __restrict__ W_div, const float* __restrict__ b_div,
        const float* __restrict__ pWcm,  const float* __restrict__ b_cm,
        float* __restrict__ pooled,
        float* __restrict__ pSim, float* __restrict__ pDiv, float* __restrict__ pCon,
        float* __restrict__ out_fsp, float* __restrict__ out_sim,
        float* __restrict__ out_div, float* __restrict__ out_con,
        unsigned int* __restrict__ flags) {
    __shared__ __align__(16) float As[KC][ASLD];
    __shared__ __align__(16) float Bs[KC][ASLD];
    __shared__ float ps[HH];
    __shared__ float simsS[SUP];
    __shared__ float pred[NCLS];
    int blk = blockIdx.x, t = threadIdx.x;

    if (blk < BB) {
        // ---- phase 1: reduce own row, publish ----
        int b = blk;
        float4 acc = make_float4(0.f, 0.f, 0.f, 0.f);
        for (int seg = 0; seg < SEG; ++seg) {
            float4 v = ((const float4*)part)[(seg * BB + b) * 256 + t];
            acc.x += v.x; acc.y += v.y; acc.z += v.z; acc.w += v.w;
        }
        const float inv = 1.0f / 512.0f;
        acc.x *= inv; acc.y *= inv; acc.z *= inv; acc.w *= inv;
        ((float4*)ps)[t] = acc;
        ((float4*)(pooled + (size_t)b * HH))[t] = acc;
        __syncthreads();                 // drains this block's global stores (vmcnt 0)
        __threadfence();                 // device-scope release
        if (t == 0)
            __hip_atomic_fetch_add(&flags[0], 1u, __ATOMIC_RELEASE, __HIP_MEMORY_SCOPE_AGENT);
        if (t == 0) {
            while (__hip_atomic_load(&flags[0], __ATOMIC_ACQUIRE, __HIP_MEMORY_SCOPE_AGENT) < BB)
                __builtin_amdgcn_s_sleep(2);
        }
        __syncthreads();
        __threadfence();                 // device-scope acquire

        // ---- fewshot ----
        int wave = t >> 6, lane = t & 63;
        for (int j = wave; j < SUP; j += 4) {
            const float* row = (j < BB) ? (pooled + (size_t)j * HH)
                                        : (supF + (size_t)j * HH);
            float s = 0.f;
#pragma unroll
            for (int q = 0; q < 16; ++q) {
                int h = lane + q * 64;
                s += ps[h] * row[h];
            }
            for (int off = 32; off; off >>= 1) s += __shfl_down(s, off);
            if (lane == 0) simsS[j] = s;
        }
        __syncthreads();

        if (t == 0) {
            float vals[KFS]; int idx[KFS];
            for (int i = 0; i < KFS; ++i) {
                float best = -3.4e38f; int bi = 0;
                for (int j = 0; j < SUP; ++j) {
                    bool taken = false;
                    for (int p = 0; p < i; ++p) taken = taken || (idx[p] == j);
                    if (!taken && simsS[j] > best) { best = simsS[j]; bi = j; }
                }
                vals[i] = best; idx[i] = bi;
            }
            float mx = vals[0];
            for (int i = 1; i < KFS; ++i) mx = fmaxf(mx, vals[i]);
            float e[KFS], sum = 0.f;
            for (int i = 0; i < KFS; ++i) { e[i] = __expf(vals[i] - mx); sum += e[i]; }
            float p0 = 0.f, p1 = 0.f, p2 = 0.f;
            for (int i = 0; i < KFS; ++i) {
                int j = idx[i];
                int lab = (j < BB) ? labels[j] : supL[j];
                float wv = e[i] / sum;
                if (lab == 0) p0 += wv;
                else if (lab == 1) p1 += wv;
                else if (lab == 2) p2 += wv;
            }
            pred[0] = p0; pred[1] = p1; pred[2] = p2;
        }
        __syncthreads();

        float p[NCLS] = {pred[0], pred[1], pred[2]};
        for (int i = t; i < SS * NCLS; i += 256) {
            int c = i - (i / NCLS) * NCLS;
            out_fsp[(size_t)b * SS * NCLS + i] = p[c];
        }
        return;
    }

    if (blk < 2 * BB) {
        // ---- phase 2: GEMM K-partials (need pooled) ----
        if (t == 0) {
            while (__hip_atomic_load(&flags[0], __ATOMIC_ACQUIRE, __HIP_MEMORY_SCOPE_AGENT) < BB)
                __builtin_amdgcn_s_sleep(2);
        }
        __syncthreads();
        __threadfence();

        int id = blk - BB;
        if (id < 16) {
            gemm64_partial(pooled, W_sim, pSim, 128, (id >> 3) * 64, (id & 7) * KB, id & 7, t, As, Bs);
        } else if (id < 32) {
            int i2 = id - 16;
            gemm64_partial(pooled, W_div, pDiv, 128, (i2 >> 3) * 64, (i2 & 7) * KB, i2 & 7, t, As, Bs);
        } else {
            // con: B rows = sum over 4 pWcm m-partials
            int i2 = id - 32;                  // 0..31: 4 n-tiles x 8 ksplit
            int n0 = (i2 >> 3) * 64, ks = i2 & 7, k0 = ks * KB;
            int tm = t >> 4, tn = t & 15;
            int lr = t >> 2, lq = t & 3;
            float acc[4][4] = {};
            for (int kc = 0; kc < KB; kc += KC) {
                int ka = k0 + kc + lq * 4;
                float4 a0 = *(const float4*)(pooled + (size_t)lr * HH + ka);
                float4 a1 = *(const float4*)(pooled + (size_t)lr * HH + ka + 16);
                float4 w0 = make_float4(0.f, 0.f, 0.f, 0.f), w1 = w0;
#pragma unroll
                for (int p = 0; p < WKS; ++p) {
                    float4 v0 = *(const float4*)(pWcm + ((size_t)p * 256 + n0 + lr) * HH + ka);
                    float4 v1 = *(const float4*)(pWcm + ((size_t)p * 256 + n0 + lr) * HH + ka + 16);
                    w0.x += v0.x; w0.y += v0.y; w0.z += v0.z; w0.w += v0.w;
                    w1.x += v1.x; w1.y += v1.y; w1.z += v1.z; w1.w += v1.w;
                }
                As[lq*4+0][lr] = a0.x; As[lq*4+1][lr] = a0.y; As[lq*4+2][lr] = a0.z; As[lq*4+3][lr] = a0.w;
                As[16+lq*4+0][lr] = a1.x; As[16+lq*4+1][lr] = a1.y; As[16+lq*4+2][lr] = a1.z; As[16+lq*4+3][lr] = a1.w;
                Bs[lq*4+0][lr] = w0.x; Bs[lq*4+1][lr] = w0.y; Bs[lq*4+2][lr] = w0.z; Bs[lq*4+3][lr] = w0.w;
                Bs[16+lq*4+0][lr] = w1.x; Bs[16+lq*4+1][lr] = w1.y; Bs[16+lq*4+2][lr] = w1.z; Bs[16+lq*4+3][lr] = w1.w;
                __syncthreads();
#pragma unroll
                for (int k = 0; k < KC; ++k) {
                    float4 a4 = *(const float4*)&As[k][tm * 4];
                    float4 b4 = *(const float4*)&Bs[k][tn * 4];
                    acc[0][0] += a4.x * b4.x; acc[0][1] += a4.x * b4.y;
                    acc[0][2] += a4.x * b4.z; acc[0][3] += a4.x * b4.w;
                    acc[1][0] += a4.y * b4.x; acc[1][1] += a4.y * b4.y;
                    acc[1][2] += a4.y * b4.z; acc[1][3] += a4.y * b4.w;
                    acc[2][0] += a4.z * b4.x; acc[2][1] += a4.z * b4.y;
                    acc[2][2] += a4.z * b4.z; acc[2][3] += a4.z * b4.w;
                    acc[3][0] += a4.w * b4.x; acc[3][1] += a4.w * b4.y;
                    acc[3][2] += a4.w * b4.z; acc[3][3] += a4.w * b4.w;
                }
                __syncthreads();
            }
#pragma unroll
            for (int i = 0; i < 4; ++i)
                *(float4*)(pCon + ((size_t)ks * 64 + tm * 4 + i) * 256 + n0 + tn * 4) =
                    make_float4(acc[i][0], acc[i][1], acc[i][2], acc[i][3]);
        }
        __syncthreads();                 // drain partial stores
        __threadfence();
        if (t == 0)
            __hip_atomic_fetch_add(&flags[1], 1u, __ATOMIC_RELEASE, __HIP_MEMORY_SCOPE_AGENT);
        return;
    }

    // ---- phase 3: combine ----
    if (t == 0) {
        while (__hip_atomic_load(&flags[1], __ATOMIC_ACQUIRE, __HIP_MEMORY_SCOPE_AGENT) < BB)
            __builtin_amdgcn_s_sleep(2);
    }
    __syncthreads();
    __threadfence();

    int gid = (blk - 2 * BB) * 256 + t;
    for (int i = gid; i < 32768; i += 2048) {
        if (i < 8192) {
            float s = b_sim[i & 127];
#pragma unroll
            for (int p = 0; p < KSPLIT; ++p) s += pSim[p * 8192 + i];
            out_sim[i] = s;
        } else if (i < 16384) {
            int i2 = i - 8192;
            float s = b_div[i2 & 127];
#pragma unroll
            for (int p = 0; p < KSPLIT; ++p) s += pDiv[p * 8192 + i2];
            out_div[i2] = s;
        } else {
            int i2 = i - 16384;
            float s = b_cm[i2 & 255];
#pragma unroll
            for (int p = 0; p < KSPLIT; ++p) s += pCon[p * 16384 + i2];
            out_con[i2] = s;
        }
    }
}

extern "C" void kernel_launch(void* const* d_in, const int* in_sizes, int n_in,
                              void* d_out, int out_size, void* d_ws, size_t ws_size,
                              hipStream_t stream) {
    const float* hs    = (const float*)d_in[0];
    const int*   lab   = (const int*)  d_in[1];
    const float* supF  = (const float*)d_in[2];
    const int*   supL  = (const int*)  d_in[3];
    const float* W_sim = (const float*)d_in[4];
    const float* b_sim = (const float*)d_in[5];
    const float* W_div = (const float*)d_in[6];
    const float* b_div = (const float*)d_in[7];
    const float* W_met = (const float*)d_in[8];
    const float* b_met = (const float*)d_in[9];
    const float* W_con = (const float*)d_in[10];
    const float* b_con = (const float*)d_in[11];

    float* out = (float*)d_out;
    float* out_fsp = out;                 // [64,512,3]
    float* out_sim = out + 98304;         // [64,128]
    float* out_div = out + 106496;        // [64,128]
    float* out_con = out + 114688;        // [64,256]

    float* ws     = (float*)d_ws;
    float* part   = ws;                                    // 2,097,152
    float* pooled = part + (size_t)SEG * BB * HH;          // 65,536
    float* pWcm   = pooled + BB * HH;                      // 1,048,576
    float* b_cm   = pWcm + (size_t)WKS * 256 * HH;         // 256
    float* pSim   = b_cm + 256;                            // 65,536
    float* pDiv   = pSim + KSPLIT * BB * 128;              // 65,536
    float* pCon   = pDiv + KSPLIT * BB * 128;              // 131,072
    unsigned int* flags = (unsigned int*)(pCon + KSPLIT * BB * 256);

    k1_pool_wgemm<<<POOL_BLKS + WG_BLKS + 1, 256, 0, stream>>>(
        hs, W_con, W_met, b_met, b_con, part, pWcm, b_cm, flags);

    k2_main<<<2 * BB + 8, 256, 0, stream>>>(
        part, supF, lab, supL, W_sim, b_sim, W_div, b_div, pWcm, b_cm,
        pooled, pSim, pDiv, pCon, out_fsp, out_sim, out_div, out_con, flags);
}

// Round 5
// 96.919 us; speedup vs baseline: 1.3179x; 1.3179x over previous
//
#include <hip/hip_runtime.h>

#define BB 64
#define SS 512
#define HH 1024
#define SUP 100
#define KFS 5
#define NCLS 3
#define SEG 32            // pool s-segments
#define KSPLIT 8          // K-split for GEMM partials
#define KB (HH / KSPLIT)  // 128
#define KC 32             // K per LDS chunk
#define ASLD 68           // padded LDS row
#define WKS 4             // W_cm m-split
#define WKB (HH / WKS)    // 256

#define POOL_BLKS (BB * SEG)   // 2048
#define WG_BLKS   256          // W_cm partial blocks

// ======================= K1: pool partials + W_cm partials + b_cm =======================
__global__ void k1_pool_wgemm(const float* __restrict__ hs,
                              const float* __restrict__ W_con,
                              const float* __restrict__ W_met,
                              const float* __restrict__ b_met,
                              const float* __restrict__ b_con,
                              float* __restrict__ part,
                              float* __restrict__ pWcm,
                              float* __restrict__ b_cm) {
    int blk = blockIdx.x, t = threadIdx.x;

    if (blk < POOL_BLKS) {                       // ---- pooling partials (HBM-bound) ----
        int b = blk >> 5, seg = blk & (SEG - 1);
        const float4* src = (const float4*)(hs + (size_t)b * SS * HH);
        float4 acc = make_float4(0.f, 0.f, 0.f, 0.f);
        int s0 = seg * (SS / SEG);
#pragma unroll
        for (int s = s0; s < s0 + (SS / SEG); ++s) {
            float4 v = src[s * 256 + t];
            acc.x += v.x; acc.y += v.y; acc.z += v.z; acc.w += v.w;
        }
        ((float4*)part)[(seg * BB + b) * 256 + t] = acc;
        return;
    }

    if (blk < POOL_BLKS + WG_BLKS) {             // ---- W_cm[o,h] partials, m-split 4 ----
        __shared__ __align__(16) float As[KC][ASLD];
        __shared__ __align__(16) float Bs[KC][ASLD];
        int id = blk - POOL_BLKS;
        int p    = id & 3;
        int tile = id >> 2;                      // 0..63
        int o0 = (tile & 3) * 64;
        int h0 = (tile >> 2) * 64;
        int m0 = p * WKB;
        int tm = t >> 4, tn = t & 15;
        int lr = t >> 2, lq = t & 3;             // A-stage: o-row, m-quad
        int mr = t >> 3, hq = t & 7;             // B-stage: m-row, h-quad
        float acc[4][4] = {};
        for (int kc = 0; kc < WKB; kc += KC) {
            int ma = m0 + kc;
            float4 a0 = *(const float4*)(W_con + (size_t)(o0 + lr) * HH + ma + lq * 4);
            float4 a1 = *(const float4*)(W_con + (size_t)(o0 + lr) * HH + ma + lq * 4 + 16);
            As[lq*4+0][lr] = a0.x; As[lq*4+1][lr] = a0.y; As[lq*4+2][lr] = a0.z; As[lq*4+3][lr] = a0.w;
            As[16+lq*4+0][lr] = a1.x; As[16+lq*4+1][lr] = a1.y; As[16+lq*4+2][lr] = a1.z; As[16+lq*4+3][lr] = a1.w;
            float4 w0 = *(const float4*)(W_met + (size_t)(ma + mr) * HH + h0 + hq * 4);
            float4 w1 = *(const float4*)(W_met + (size_t)(ma + mr) * HH + h0 + hq * 4 + 32);
            *(float4*)&Bs[mr][hq * 4]      = w0;
            *(float4*)&Bs[mr][hq * 4 + 32] = w1;
            __syncthreads();
#pragma unroll
            for (int k = 0; k < KC; ++k) {
                float4 a4 = *(const float4*)&As[k][tm * 4];
                float4 b4 = *(const float4*)&Bs[k][tn * 4];
                acc[0][0] += a4.x * b4.x; acc[0][1] += a4.x * b4.y;
                acc[0][2] += a4.x * b4.z; acc[0][3] += a4.x * b4.w;
                acc[1][0] += a4.y * b4.x; acc[1][1] += a4.y * b4.y;
                acc[1][2] += a4.y * b4.z; acc[1][3] += a4.y * b4.w;
                acc[2][0] += a4.z * b4.x; acc[2][1] += a4.z * b4.y;
                acc[2][2] += a4.z * b4.z; acc[2][3] += a4.z * b4.w;
                acc[3][0] += a4.w * b4.x; acc[3][1] += a4.w * b4.y;
                acc[3][2] += a4.w * b4.z; acc[3][3] += a4.w * b4.w;
            }
            __syncthreads();
        }
#pragma unroll
        for (int i = 0; i < 4; ++i)
            *(float4*)(pWcm + ((size_t)p * 256 + o0 + tm * 4 + i) * HH + h0 + tn * 4) =
                make_float4(acc[i][0], acc[i][1], acc[i][2], acc[i][3]);
        return;
    }

    // ---- last block: b_cm[o] = dot(W_con[o,:], b_met) + b_con[o] ----
    float s = b_con[t];
    const float4* wr  = (const float4*)(W_con + (size_t)t * HH);
    const float4* bm4 = (const float4*)b_met;
#pragma unroll 8
    for (int m = 0; m < HH / 4; ++m) {
        float4 w = wr[m], bm = bm4[m];
        s += w.x * bm.x + w.y * bm.y + w.z * bm.z + w.w * bm.w;
    }
    b_cm[t] = s;
}

// ======================= K2: reduce partials -> pooled =======================
__global__ void pool_reduce(const float* __restrict__ part, float* __restrict__ pooled) {
    int b = blockIdx.x;
    int t = threadIdx.x;
    float4 acc = make_float4(0.f, 0.f, 0.f, 0.f);
#pragma unroll 4
    for (int seg = 0; seg < SEG; ++seg) {
        float4 v = ((const float4*)part)[(seg * BB + b) * 256 + t];
        acc.x += v.x; acc.y += v.y; acc.z += v.z; acc.w += v.w;
    }
    const float inv = 1.0f / 512.0f;
    acc.x *= inv; acc.y *= inv; acc.z *= inv; acc.w *= inv;
    ((float4*)pooled)[b * 256 + t] = acc;
}

// ---------------- 64x64 K-partial GEMM tile ----------------
__device__ __forceinline__ void gemm64_partial(const float* __restrict__ A,
                                               const float* __restrict__ W,
                                               float* __restrict__ partOut, int N,
                                               int n0, int k0, int ks, int t,
                                               float (*As)[ASLD], float (*Bs)[ASLD]) {
    int tm = t >> 4, tn = t & 15;
    int lr = t >> 2, lq = t & 3;
    float acc[4][4] = {};
    for (int kc = 0; kc < KB; kc += KC) {
        int ka = k0 + kc + lq * 4;
        float4 a0 = *(const float4*)(A + (size_t)lr * HH + ka);
        float4 a1 = *(const float4*)(A + (size_t)lr * HH + ka + 16);
        float4 w0 = *(const float4*)(W + (size_t)(n0 + lr) * HH + ka);
        float4 w1 = *(const float4*)(W + (size_t)(n0 + lr) * HH + ka + 16);
        As[lq*4+0][lr] = a0.x; As[lq*4+1][lr] = a0.y; As[lq*4+2][lr] = a0.z; As[lq*4+3][lr] = a0.w;
        As[16+lq*4+0][lr] = a1.x; As[16+lq*4+1][lr] = a1.y; As[16+lq*4+2][lr] = a1.z; As[16+lq*4+3][lr] = a1.w;
        Bs[lq*4+0][lr] = w0.x; Bs[lq*4+1][lr] = w0.y; Bs[lq*4+2][lr] = w0.z; Bs[lq*4+3][lr] = w0.w;
        Bs[16+lq*4+0][lr] = w1.x; Bs[16+lq*4+1][lr] = w1.y; Bs[16+lq*4+2][lr] = w1.z; Bs[16+lq*4+3][lr] = w1.w;
        __syncthreads();
#pragma unroll
        for (int k = 0; k < KC; ++k) {
            float4 a4 = *(const float4*)&As[k][tm * 4];
            float4 b4 = *(const float4*)&Bs[k][tn * 4];
            acc[0][0] += a4.x * b4.x; acc[0][1] += a4.x * b4.y;
            acc[0][2] += a4.x * b4.z; acc[0][3] += a4.x * b4.w;
            acc[1][0] += a4.y * b4.x; acc[1][1] += a4.y * b4.y;
            acc[1][2] += a4.y * b4.z; acc[1][3] += a4.y * b4.w;
            acc[2][0] += a4.z * b4.x; acc[2][1] += a4.z * b4.y;
            acc[2][2] += a4.z * b4.z; acc[2][3] += a4.z * b4.w;
            acc[3][0] += a4.w * b4.x; acc[3][1] += a4.w * b4.y;
            acc[3][2] += a4.w * b4.z; acc[3][3] += a4.w * b4.w;
        }
        __syncthreads();
    }
#pragma unroll
    for (int i = 0; i < 4; ++i)
        *(float4*)(partOut + ((size_t)ks * 64 + tm * 4 + i) * N + n0 + tn * 4) =
            make_float4(acc[i][0], acc[i][1], acc[i][2], acc[i][3]);
}

// ======================= K3: all GEMM K-partials (80 blocks) =======================
// [0,16) sim | [16,32) div | [32,64) con(pWcm-summed) | [64,80) sims(pooled/supF rows)
__global__ void lin_partial(const float* __restrict__ pooled,
                            const float* __restrict__ W_sim,
                            const float* __restrict__ W_div,
                            const float* __restrict__ pWcm,
                            const float* __restrict__ supF,
                            float* __restrict__ pSim, float* __restrict__ pDiv,
                            float* __restrict__ pCon, float* __restrict__ pSims) {
    __shared__ __align__(16) float As[KC][ASLD];
    __shared__ __align__(16) float Bs[KC][ASLD];
    int id = blockIdx.x, t = threadIdx.x;

    if (id < 16) {
        gemm64_partial(pooled, W_sim, pSim, 128, (id >> 3) * 64, (id & 7) * KB, id & 7, t, As, Bs);
        return;
    }
    if (id < 32) {
        int i2 = id - 16;
        gemm64_partial(pooled, W_div, pDiv, 128, (i2 >> 3) * 64, (i2 & 7) * KB, i2 & 7, t, As, Bs);
        return;
    }

    int tm = t >> 4, tn = t & 15;
    int lr = t >> 2, lq = t & 3;
    float acc[4][4] = {};

    if (id < 64) {
        // ---- con: B rows = sum over 4 pWcm m-partials ----
        int i2 = id - 32;                  // 0..31: 4 n-tiles x 8 ksplit
        int n0 = (i2 >> 3) * 64, ks = i2 & 7, k0 = ks * KB;
        for (int kc = 0; kc < KB; kc += KC) {
            int ka = k0 + kc + lq * 4;
            float4 a0 = *(const float4*)(pooled + (size_t)lr * HH + ka);
            float4 a1 = *(const float4*)(pooled + (size_t)lr * HH + ka + 16);
            float4 w0 = make_float4(0.f, 0.f, 0.f, 0.f), w1 = w0;
#pragma unroll
            for (int p = 0; p < WKS; ++p) {
                float4 v0 = *(const float4*)(pWcm + ((size_t)p * 256 + n0 + lr) * HH + ka);
                float4 v1 = *(const float4*)(pWcm + ((size_t)p * 256 + n0 + lr) * HH + ka + 16);
                w0.x += v0.x; w0.y += v0.y; w0.z += v0.z; w0.w += v0.w;
                w1.x += v1.x; w1.y += v1.y; w1.z += v1.z; w1.w += v1.w;
            }
            As[lq*4+0][lr] = a0.x; As[lq*4+1][lr] = a0.y; As[lq*4+2][lr] = a0.z; As[lq*4+3][lr] = a0.w;
            As[16+lq*4+0][lr] = a1.x; As[16+lq*4+1][lr] = a1.y; As[16+lq*4+2][lr] = a1.z; As[16+lq*4+3][lr] = a1.w;
            Bs[lq*4+0][lr] = w0.x; Bs[lq*4+1][lr] = w0.y; Bs[lq*4+2][lr] = w0.z; Bs[lq*4+3][lr] = w0.w;
            Bs[16+lq*4+0][lr] = w1.x; Bs[16+lq*4+1][lr] = w1.y; Bs[16+lq*4+2][lr] = w1.z; Bs[16+lq*4+3][lr] = w1.w;
            __syncthreads();
#pragma unroll
            for (int k = 0; k < KC; ++k) {
                float4 a4 = *(const float4*)&As[k][tm * 4];
                float4 b4 = *(const float4*)&Bs[k][tn * 4];
                acc[0][0] += a4.x * b4.x; acc[0][1] += a4.x * b4.y;
                acc[0][2] += a4.x * b4.z; acc[0][3] += a4.x * b4.w;
                acc[1][0] += a4.y * b4.x; acc[1][1] += a4.y * b4.y;
                acc[1][2] += a4.y * b4.z; acc[1][3] += a4.y * b4.w;
                acc[2][0] += a4.z * b4.x; acc[2][1] += a4.z * b4.y;
                acc[2][2] += a4.z * b4.z; acc[2][3] += a4.z * b4.w;
                acc[3][0] += a4.w * b4.x; acc[3][1] += a4.w * b4.y;
                acc[3][2] += a4.w * b4.z; acc[3][3] += a4.w * b4.w;
            }
            __syncthreads();
        }
#pragma unroll
        for (int i = 0; i < 4; ++i)
            *(float4*)(pCon + ((size_t)ks * 64 + tm * 4 + i) * 256 + n0 + tn * 4) =
                make_float4(acc[i][0], acc[i][1], acc[i][2], acc[i][3]);
        return;
    }

    // ---- sims: B row j -> pooled (j<64) else supF (clamped at 99; j>=100 garbage, never read) ----
    {
        int i2 = id - 64;                  // 0..15: 2 n-tiles x 8 ksplit
        int n0 = (i2 >> 3) * 64, ks = i2 & 7, k0 = ks * KB;
        int j = n0 + lr;
        const float* wrow = (j < BB) ? (pooled + (size_t)j * HH)
                                     : (supF + (size_t)(j < SUP ? j : SUP - 1) * HH);
        for (int kc = 0; kc < KB; kc += KC) {
            int ka = k0 + kc + lq * 4;
            float4 a0 = *(const float4*)(pooled + (size_t)lr * HH + ka);
            float4 a1 = *(const float4*)(pooled + (size_t)lr * HH + ka + 16);
            float4 w0 = *(const float4*)(wrow + ka);
            float4 w1 = *(const float4*)(wrow + ka + 16);
            As[lq*4+0][lr] = a0.x; As[lq*4+1][lr] = a0.y; As[lq*4+2][lr] = a0.z; As[lq*4+3][lr] = a0.w;
            As[16+lq*4+0][lr] = a1.x; As[16+lq*4+1][lr] = a1.y; As[16+lq*4+2][lr] = a1.z; As[16+lq*4+3][lr] = a1.w;
            Bs[lq*4+0][lr] = w0.x; Bs[lq*4+1][lr] = w0.y; Bs[lq*4+2][lr] = w0.z; Bs[lq*4+3][lr] = w0.w;
            Bs[16+lq*4+0][lr] = w1.x; Bs[16+lq*4+1][lr] = w1.y; Bs[16+lq*4+2][lr] = w1.z; Bs[16+lq*4+3][lr] = w1.w;
            __syncthreads();
#pragma unroll
            for (int k = 0; k < KC; ++k) {
                float4 a4 = *(const float4*)&As[k][tm * 4];
                float4 b4 = *(const float4*)&Bs[k][tn * 4];
                acc[0][0] += a4.x * b4.x; acc[0][1] += a4.x * b4.y;
                acc[0][2] += a4.x * b4.z; acc[0][3] += a4.x * b4.w;
                acc[1][0] += a4.y * b4.x; acc[1][1] += a4.y * b4.y;
                acc[1][2] += a4.y * b4.z; acc[1][3] += a4.y * b4.w;
                acc[2][0] += a4.z * b4.x; acc[2][1] += a4.z * b4.y;
                acc[2][2] += a4.z * b4.z; acc[2][3] += a4.z * b4.w;
                acc[3][0] += a4.w * b4.x; acc[3][1] += a4.w * b4.y;
                acc[3][2] += a4.w * b4.z; acc[3][3] += a4.w * b4.w;
            }
            __syncthreads();
        }
#pragma unroll
        for (int i = 0; i < 4; ++i)
            *(float4*)(pSims + ((size_t)ks * 64 + tm * 4 + i) * 128 + n0 + tn * 4) =
                make_float4(acc[i][0], acc[i][1], acc[i][2], acc[i][3]);
    }
}

// ======================= K4: fewshot finalize + combine (64 blocks) =======================
__global__ void k4_final(const float* __restrict__ pSims,
                         const int* __restrict__ labels,
                         const int* __restrict__ supL,
                         const float* __restrict__ pSim, const float* __restrict__ b_sim,
                         const float* __restrict__ pDiv, const float* __restrict__ b_div,
                         const float* __restrict__ pCon, const float* __restrict__ b_cm,
                         float* __restrict__ out_fsp, float* __restrict__ out_sim,
                         float* __restrict__ out_div, float* __restrict__ out_con) {
    __shared__ float simsS[128];
    __shared__ float pred[NCLS];
    int b = blockIdx.x, t = threadIdx.x;

    if (t < 128) {
        float s = 0.f;
#pragma unroll
        for (int ks = 0; ks < KSPLIT; ++ks)
            s += pSims[((size_t)ks * 64 + b) * 128 + t];
        simsS[t] = s;
    }
    __syncthreads();

    if (t == 0) {
        float vals[KFS]; int idx[KFS];
        for (int i = 0; i < KFS; ++i) {
            float best = -3.4e38f; int bi = 0;
            for (int j = 0; j < SUP; ++j) {
                bool taken = false;
                for (int p = 0; p < i; ++p) taken = taken || (idx[p] == j);
                if (!taken && simsS[j] > best) { best = simsS[j]; bi = j; }
            }
            vals[i] = best; idx[i] = bi;
        }
        float mx = vals[0];
        for (int i = 1; i < KFS; ++i) mx = fmaxf(mx, vals[i]);
        float e[KFS], sum = 0.f;
        for (int i = 0; i < KFS; ++i) { e[i] = __expf(vals[i] - mx); sum += e[i]; }
        float p0 = 0.f, p1 = 0.f, p2 = 0.f;
        for (int i = 0; i < KFS; ++i) {
            int j = idx[i];
            int lab = (j < BB) ? labels[j] : supL[j];
            float wv = e[i] / sum;
            if (lab == 0) p0 += wv;
            else if (lab == 1) p1 += wv;
            else if (lab == 2) p2 += wv;
        }
        pred[0] = p0; pred[1] = p1; pred[2] = p2;
    }
    __syncthreads();

    float p[NCLS] = {pred[0], pred[1], pred[2]};
    for (int i = t; i < SS * NCLS; i += 256) {
        int c = i - (i / NCLS) * NCLS;
        out_fsp[(size_t)b * SS * NCLS + i] = p[c];
    }

    // ---- combine slice: this block handles [b*512, b*512+512) of the 32768-elem space ----
#pragma unroll
    for (int rep = 0; rep < 2; ++rep) {
        int i = b * 512 + rep * 256 + t;
        if (i < 8192) {
            float s = b_sim[i & 127];
#pragma unroll
            for (int p2 = 0; p2 < KSPLIT; ++p2) s += pSim[p2 * 8192 + i];
            out_sim[i] = s;
        } else if (i < 16384) {
            int i2 = i - 8192;
            float s = b_div[i2 & 127];
#pragma unroll
            for (int p2 = 0; p2 < KSPLIT; ++p2) s += pDiv[p2 * 8192 + i2];
            out_div[i2] = s;
        } else {
            int i2 = i - 16384;
            float s = b_cm[i2 & 255];
#pragma unroll
            for (int p2 = 0; p2 < KSPLIT; ++p2) s += pCon[p2 * 16384 + i2];
            out_con[i2] = s;
        }
    }
}

extern "C" void kernel_launch(void* const* d_in, const int* in_sizes, int n_in,
                              void* d_out, int out_size, void* d_ws, size_t ws_size,
                              hipStream_t stream) {
    const float* hs    = (const float*)d_in[0];
    const int*   lab   = (const int*)  d_in[1];
    const float* supF  = (const float*)d_in[2];
    const int*   supL  = (const int*)  d_in[3];
    const float* W_sim = (const float*)d_in[4];
    const float* b_sim = (const float*)d_in[5];
    const float* W_div = (const float*)d_in[6];
    const float* b_div = (const float*)d_in[7];
    const float* W_met = (const float*)d_in[8];
    const float* b_met = (const float*)d_in[9];
    const float* W_con = (const float*)d_in[10];
    const float* b_con = (const float*)d_in[11];

    float* out = (float*)d_out;
    float* out_fsp = out;                 // [64,512,3]
    float* out_sim = out + 98304;         // [64,128]
    float* out_div = out + 106496;        // [64,128]
    float* out_con = out + 114688;        // [64,256]

    float* ws     = (float*)d_ws;
    float* part   = ws;                                    // 2,097,152
    float* pooled = part + (size_t)SEG * BB * HH;          // 65,536
    float* pWcm   = pooled + BB * HH;                      // 1,048,576
    float* b_cm   = pWcm + (size_t)WKS * 256 * HH;         // 256
    float* pSim   = b_cm + 256;                            // 65,536
    float* pDiv   = pSim + KSPLIT * BB * 128;              // 65,536
    float* pCon   = pDiv + KSPLIT * BB * 128;              // 131,072
    float* pSims  = pCon + KSPLIT * BB * 256;              // 65,536

    k1_pool_wgemm<<<POOL_BLKS + WG_BLKS + 1, 256, 0, stream>>>(
        hs, W_con, W_met, b_met, b_con, part, pWcm, b_cm);

    pool_reduce<<<BB, 256, 0, stream>>>(part, pooled);

    lin_partial<<<80, 256, 0, stream>>>(pooled, W_sim, W_div, pWcm, supF,
                                        pSim, pDiv, pCon, pSims);

    k4_final<<<BB, 256, 0, stream>>>(pSims, lab, supL, pSim, b_sim, pDiv, b_div,
                                     pCon, b_cm, out_fsp, out_sim, out_div, out_con);
}

// Round 6
// 69.638 us; speedup vs baseline: 1.8341x; 1.3917x over previous
//
#include <hip/hip_runtime.h>

#define BB 64
#define SS 512
#define HH 1024
#define SUP 100
#define KFS 5
#define NCLS 3
#define SEG 32            // pool s-segments: 2048 blocks, 16 rows each
#define KSPLIT 8          // K-split for GEMM partials
#define KB (HH / KSPLIT)  // 128
#define KC 32             // K per LDS chunk
#define ASLD 68           // padded LDS row

// ======================= K1: pool partials — pure streaming, max ILP =======================
// 2048 blocks x 256 thr. Each thread: 16 independent float4 loads (in flight together),
// tree-sum, one float4 partial write. No LDS.
__global__ void pool_partial(const float* __restrict__ hs, float* __restrict__ part) {
    int blk = blockIdx.x;
    int b   = blk >> 5;
    int seg = blk & (SEG - 1);
    int t   = threadIdx.x;
    const float4* src = (const float4*)(hs + (size_t)b * SS * HH) + (size_t)(seg * 16) * 256 + t;
    float4 v[16];
#pragma unroll
    for (int i = 0; i < 16; ++i) v[i] = src[(size_t)i * 256];
    // tree reduction (keeps loads independent of adds)
#pragma unroll
    for (int st = 8; st; st >>= 1)
#pragma unroll
        for (int i = 0; i < st; ++i) {
            v[i].x += v[i + st].x; v[i].y += v[i + st].y;
            v[i].z += v[i + st].z; v[i].w += v[i + st].w;
        }
    ((float4*)part)[(size_t)(seg * BB + b) * 256 + t] = v[0];
}

// ======================= K2: reduce partials -> pooled =======================
__global__ void pool_reduce(const float* __restrict__ part, float* __restrict__ pooled) {
    int b = blockIdx.x;
    int t = threadIdx.x;
    float4 acc = make_float4(0.f, 0.f, 0.f, 0.f);
#pragma unroll 4
    for (int seg = 0; seg < SEG; ++seg) {
        float4 v = ((const float4*)part)[(size_t)(seg * BB + b) * 256 + t];
        acc.x += v.x; acc.y += v.y; acc.z += v.z; acc.w += v.w;
    }
    const float inv = 1.0f / 512.0f;
    acc.x *= inv; acc.y *= inv; acc.z *= inv; acc.w *= inv;
    ((float4*)pooled)[b * 256 + t] = acc;
}

// ---------------- 64x64 K-partial GEMM tile ----------------
__device__ __forceinline__ void gemm64_partial(const float* __restrict__ A,
                                               const float* __restrict__ W,
                                               float* __restrict__ partOut, int N,
                                               int n0, int k0, int ks, int t,
                                               float (*As)[ASLD], float (*Bs)[ASLD]) {
    int tm = t >> 4, tn = t & 15;
    int lr = t >> 2, lq = t & 3;
    float acc[4][4] = {};
    for (int kc = 0; kc < KB; kc += KC) {
        int ka = k0 + kc + lq * 4;
        float4 a0 = *(const float4*)(A + (size_t)lr * HH + ka);
        float4 a1 = *(const float4*)(A + (size_t)lr * HH + ka + 16);
        float4 w0 = *(const float4*)(W + (size_t)(n0 + lr) * HH + ka);
        float4 w1 = *(const float4*)(W + (size_t)(n0 + lr) * HH + ka + 16);
        As[lq*4+0][lr] = a0.x; As[lq*4+1][lr] = a0.y; As[lq*4+2][lr] = a0.z; As[lq*4+3][lr] = a0.w;
        As[16+lq*4+0][lr] = a1.x; As[16+lq*4+1][lr] = a1.y; As[16+lq*4+2][lr] = a1.z; As[16+lq*4+3][lr] = a1.w;
        Bs[lq*4+0][lr] = w0.x; Bs[lq*4+1][lr] = w0.y; Bs[lq*4+2][lr] = w0.z; Bs[lq*4+3][lr] = w0.w;
        Bs[16+lq*4+0][lr] = w1.x; Bs[16+lq*4+1][lr] = w1.y; Bs[16+lq*4+2][lr] = w1.z; Bs[16+lq*4+3][lr] = w1.w;
        __syncthreads();
#pragma unroll
        for (int k = 0; k < KC; ++k) {
            float4 a4 = *(const float4*)&As[k][tm * 4];
            float4 b4 = *(const float4*)&Bs[k][tn * 4];
            acc[0][0] += a4.x * b4.x; acc[0][1] += a4.x * b4.y;
            acc[0][2] += a4.x * b4.z; acc[0][3] += a4.x * b4.w;
            acc[1][0] += a4.y * b4.x; acc[1][1] += a4.y * b4.y;
            acc[1][2] += a4.y * b4.z; acc[1][3] += a4.y * b4.w;
            acc[2][0] += a4.z * b4.x; acc[2][1] += a4.z * b4.y;
            acc[2][2] += a4.z * b4.z; acc[2][3] += a4.z * b4.w;
            acc[3][0] += a4.w * b4.x; acc[3][1] += a4.w * b4.y;
            acc[3][2] += a4.w * b4.z; acc[3][3] += a4.w * b4.w;
        }
        __syncthreads();
    }
#pragma unroll
    for (int i = 0; i < 4; ++i)
        *(float4*)(partOut + ((size_t)ks * 64 + tm * 4 + i) * N + n0 + tn * 4) =
            make_float4(acc[i][0], acc[i][1], acc[i][2], acc[i][3]);
}

// ======================= K3: GEMM K-partials (176 blocks) =======================
// [0,16) sim | [16,32) div | [32,160) meta | [160,176) sims
__global__ void lin_partial(const float* __restrict__ pooled,
                            const float* __restrict__ W_sim,
                            const float* __restrict__ W_div,
                            const float* __restrict__ W_met,
                            const float* __restrict__ supF,
                            float* __restrict__ pSim, float* __restrict__ pDiv,
                            float* __restrict__ pMet, float* __restrict__ pSims) {
    __shared__ __align__(16) float As[KC][ASLD];
    __shared__ __align__(16) float Bs[KC][ASLD];
    int id = blockIdx.x, t = threadIdx.x;

    if (id < 16) {
        gemm64_partial(pooled, W_sim, pSim, 128, (id >> 3) * 64, (id & 7) * KB, id & 7, t, As, Bs);
        return;
    }
    if (id < 32) {
        int i2 = id - 16;
        gemm64_partial(pooled, W_div, pDiv, 128, (i2 >> 3) * 64, (i2 & 7) * KB, i2 & 7, t, As, Bs);
        return;
    }
    if (id < 160) {
        int i2 = id - 32;                 // 16 n-tiles x 8 ksplit
        gemm64_partial(pooled, W_met, pMet, 1024, (i2 >> 3) * 64, (i2 & 7) * KB, i2 & 7, t, As, Bs);
        return;
    }

    // ---- sims: B row j -> pooled (j<64) else supF (clamped at 99; j>=100 garbage, never read) ----
    {
        int i2 = id - 160;                // 0..15: 2 n-tiles x 8 ksplit
        int n0 = (i2 >> 3) * 64, ks = i2 & 7, k0 = ks * KB;
        int tm = t >> 4, tn = t & 15;
        int lr = t >> 2, lq = t & 3;
        float acc[4][4] = {};
        int j = n0 + lr;
        const float* wrow = (j < BB) ? (pooled + (size_t)j * HH)
                                     : (supF + (size_t)(j < SUP ? j : SUP - 1) * HH);
        for (int kc = 0; kc < KB; kc += KC) {
            int ka = k0 + kc + lq * 4;
            float4 a0 = *(const float4*)(pooled + (size_t)lr * HH + ka);
            float4 a1 = *(const float4*)(pooled + (size_t)lr * HH + ka + 16);
            float4 w0 = *(const float4*)(wrow + ka);
            float4 w1 = *(const float4*)(wrow + ka + 16);
            As[lq*4+0][lr] = a0.x; As[lq*4+1][lr] = a0.y; As[lq*4+2][lr] = a0.z; As[lq*4+3][lr] = a0.w;
            As[16+lq*4+0][lr] = a1.x; As[16+lq*4+1][lr] = a1.y; As[16+lq*4+2][lr] = a1.z; As[16+lq*4+3][lr] = a1.w;
            Bs[lq*4+0][lr] = w0.x; Bs[lq*4+1][lr] = w0.y; Bs[lq*4+2][lr] = w0.z; Bs[lq*4+3][lr] = w0.w;
            Bs[16+lq*4+0][lr] = w1.x; Bs[16+lq*4+1][lr] = w1.y; Bs[16+lq*4+2][lr] = w1.z; Bs[16+lq*4+3][lr] = w1.w;
            __syncthreads();
#pragma unroll
            for (int k = 0; k < KC; ++k) {
                float4 a4 = *(const float4*)&As[k][tm * 4];
                float4 b4 = *(const float4*)&Bs[k][tn * 4];
                acc[0][0] += a4.x * b4.x; acc[0][1] += a4.x * b4.y;
                acc[0][2] += a4.x * b4.z; acc[0][3] += a4.x * b4.w;
                acc[1][0] += a4.y * b4.x; acc[1][1] += a4.y * b4.y;
                acc[1][2] += a4.y * b4.z; acc[1][3] += a4.y * b4.w;
                acc[2][0] += a4.z * b4.x; acc[2][1] += a4.z * b4.y;
                acc[2][2] += a4.z * b4.z; acc[2][3] += a4.z * b4.w;
                acc[3][0] += a4.w * b4.x; acc[3][1] += a4.w * b4.y;
                acc[3][2] += a4.w * b4.z; acc[3][3] += a4.w * b4.w;
            }
            __syncthreads();
        }
#pragma unroll
        for (int i = 0; i < 4; ++i)
            *(float4*)(pSims + ((size_t)ks * 64 + tm * 4 + i) * 128 + n0 + tn * 4) =
                make_float4(acc[i][0], acc[i][1], acc[i][2], acc[i][3]);
    }
}

// ======================= K4: fewshot finalize (0..63) + con partials (64..95) =======================
__global__ void k4_tail(const float* __restrict__ pSims,
                        const int* __restrict__ labels,
                        const int* __restrict__ supL,
                        const float* __restrict__ pMet,
                        const float* __restrict__ b_met,
                        const float* __restrict__ W_con,
                        float* __restrict__ pCon,
                        float* __restrict__ out_fsp) {
    __shared__ __align__(16) float As[KC][ASLD];
    __shared__ __align__(16) float Bs[KC][ASLD];
    __shared__ float simsS[128];
    __shared__ float pred[NCLS];
    int blk = blockIdx.x, t = threadIdx.x;

    if (blk >= BB) {
        // con partial: A = meta_mean (sum 8 pMet partials + b_met), W = W_con [256,1024]
        int id = blk - BB;                 // 0..31: 4 n-tiles x 8 ksplit
        int n0 = (id >> 3) * 64, ks = id & 7, k0 = ks * KB;
        int tm = t >> 4, tn = t & 15;
        int lr = t >> 2, lq = t & 3;
        float acc[4][4] = {};
        for (int kc = 0; kc < KB; kc += KC) {
            int ka = k0 + kc + lq * 4;
            float4 s0 = *(const float4*)(b_met + ka);
            float4 s1 = *(const float4*)(b_met + ka + 16);
#pragma unroll
            for (int p = 0; p < KSPLIT; ++p) {
                float4 v0 = *(const float4*)(pMet + ((size_t)p * 64 + lr) * HH + ka);
                float4 v1 = *(const float4*)(pMet + ((size_t)p * 64 + lr) * HH + ka + 16);
                s0.x += v0.x; s0.y += v0.y; s0.z += v0.z; s0.w += v0.w;
                s1.x += v1.x; s1.y += v1.y; s1.z += v1.z; s1.w += v1.w;
            }
            float4 w0 = *(const float4*)(W_con + (size_t)(n0 + lr) * HH + ka);
            float4 w1 = *(const float4*)(W_con + (size_t)(n0 + lr) * HH + ka + 16);
            As[lq*4+0][lr] = s0.x; As[lq*4+1][lr] = s0.y; As[lq*4+2][lr] = s0.z; As[lq*4+3][lr] = s0.w;
            As[16+lq*4+0][lr] = s1.x; As[16+lq*4+1][lr] = s1.y; As[16+lq*4+2][lr] = s1.z; As[16+lq*4+3][lr] = s1.w;
            Bs[lq*4+0][lr] = w0.x; Bs[lq*4+1][lr] = w0.y; Bs[lq*4+2][lr] = w0.z; Bs[lq*4+3][lr] = w0.w;
            Bs[16+lq*4+0][lr] = w1.x; Bs[16+lq*4+1][lr] = w1.y; Bs[16+lq*4+2][lr] = w1.z; Bs[16+lq*4+3][lr] = w1.w;
            __syncthreads();
#pragma unroll
            for (int k = 0; k < KC; ++k) {
                float4 a4 = *(const float4*)&As[k][tm * 4];
                float4 b4 = *(const float4*)&Bs[k][tn * 4];
                acc[0][0] += a4.x * b4.x; acc[0][1] += a4.x * b4.y;
                acc[0][2] += a4.x * b4.z; acc[0][3] += a4.x * b4.w;
                acc[1][0] += a4.y * b4.x; acc[1][1] += a4.y * b4.y;
                acc[1][2] += a4.y * b4.z; acc[1][3] += a4.y * b4.w;
                acc[2][0] += a4.z * b4.x; acc[2][1] += a4.z * b4.y;
                acc[2][2] += a4.z * b4.z; acc[2][3] += a4.z * b4.w;
                acc[3][0] += a4.w * b4.x; acc[3][1] += a4.w * b4.y;
                acc[3][2] += a4.w * b4.z; acc[3][3] += a4.w * b4.w;
            }
            __syncthreads();
        }
#pragma unroll
        for (int i = 0; i < 4; ++i)
            *(float4*)(pCon + ((size_t)ks * 64 + tm * 4 + i) * 256 + n0 + tn * 4) =
                make_float4(acc[i][0], acc[i][1], acc[i][2], acc[i][3]);
        return;
    }

    // ---- fewshot finalize ----
    int b = blk;
    if (t < 128) {
        float s = 0.f;
#pragma unroll
        for (int ks = 0; ks < KSPLIT; ++ks)
            s += pSims[((size_t)ks * 64 + b) * 128 + t];
        simsS[t] = s;
    }
    __syncthreads();

    if (t == 0) {
        float vals[KFS]; int idx[KFS];
        for (int i = 0; i < KFS; ++i) {
            float best = -3.4e38f; int bi = 0;
            for (int j = 0; j < SUP; ++j) {
                bool taken = false;
                for (int p = 0; p < i; ++p) taken = taken || (idx[p] == j);
                if (!taken && simsS[j] > best) { best = simsS[j]; bi = j; }
            }
            vals[i] = best; idx[i] = bi;
        }
        float mx = vals[0];
        for (int i = 1; i < KFS; ++i) mx = fmaxf(mx, vals[i]);
        float e[KFS], sum = 0.f;
        for (int i = 0; i < KFS; ++i) { e[i] = __expf(vals[i] - mx); sum += e[i]; }
        float p0 = 0.f, p1 = 0.f, p2 = 0.f;
        for (int i = 0; i < KFS; ++i) {
            int j = idx[i];
            int lab = (j < BB) ? labels[j] : supL[j];
            float wv = e[i] / sum;
            if (lab == 0) p0 += wv;
            else if (lab == 1) p1 += wv;
            else if (lab == 2) p2 += wv;
        }
        pred[0] = p0; pred[1] = p1; pred[2] = p2;
    }
    __syncthreads();

    float p[NCLS] = {pred[0], pred[1], pred[2]};
    for (int i = t; i < SS * NCLS; i += 256) {
        int c = i - (i / NCLS) * NCLS;
        out_fsp[(size_t)b * SS * NCLS + i] = p[c];
    }
}

// ======================= K5: combine partials + bias -> sim/div/con =======================
__global__ void combine(const float* __restrict__ pSim, const float* __restrict__ b_sim,
                        const float* __restrict__ pDiv, const float* __restrict__ b_div,
                        const float* __restrict__ pCon, const float* __restrict__ b_con,
                        float* __restrict__ out_sim, float* __restrict__ out_div,
                        float* __restrict__ out_con) {
    int gid = blockIdx.x * 256 + threadIdx.x;
    if (gid < 8192) {
        float s = b_sim[gid & 127];
#pragma unroll
        for (int p = 0; p < KSPLIT; ++p) s += pSim[p * 8192 + gid];
        out_sim[gid] = s;
    } else if (gid < 16384) {
        int i = gid - 8192;
        float s = b_div[i & 127];
#pragma unroll
        for (int p = 0; p < KSPLIT; ++p) s += pDiv[p * 8192 + i];
        out_div[i] = s;
    } else {
        int i = gid - 16384;
        float s = b_con[i & 255];
#pragma unroll
        for (int p = 0; p < KSPLIT; ++p) s += pCon[p * 16384 + i];
        out_con[i] = s;
    }
}

extern "C" void kernel_launch(void* const* d_in, const int* in_sizes, int n_in,
                              void* d_out, int out_size, void* d_ws, size_t ws_size,
                              hipStream_t stream) {
    const float* hs    = (const float*)d_in[0];
    const int*   lab   = (const int*)  d_in[1];
    const float* supF  = (const float*)d_in[2];
    const int*   supL  = (const int*)  d_in[3];
    const float* W_sim = (const float*)d_in[4];
    const float* b_sim = (const float*)d_in[5];
    const float* W_div = (const float*)d_in[6];
    const float* b_div = (const float*)d_in[7];
    const float* W_met = (const float*)d_in[8];
    const float* b_met = (const float*)d_in[9];
    const float* W_con = (const float*)d_in[10];
    const float* b_con = (const float*)d_in[11];

    float* out = (float*)d_out;
    float* out_fsp = out;                 // [64,512,3]
    float* out_sim = out + 98304;         // [64,128]
    float* out_div = out + 106496;        // [64,128]
    float* out_con = out + 114688;        // [64,256]

    float* ws     = (float*)d_ws;
    float* part   = ws;                                    // 2,097,152
    float* pooled = part + (size_t)SEG * BB * HH;          // 65,536
    float* pSim   = pooled + BB * HH;                      // 65,536
    float* pDiv   = pSim + KSPLIT * BB * 128;              // 65,536
    float* pMet   = pDiv + KSPLIT * BB * 128;              // 524,288
    float* pCon   = pMet + (size_t)KSPLIT * BB * HH;       // 131,072
    float* pSims  = pCon + KSPLIT * BB * 256;              // 65,536

    pool_partial<<<BB * SEG, 256, 0, stream>>>(hs, part);
    pool_reduce <<<BB,       256, 0, stream>>>(part, pooled);
    lin_partial <<<176,      256, 0, stream>>>(pooled, W_sim, W_div, W_met, supF,
                                               pSim, pDiv, pMet, pSims);
    k4_tail     <<<96,       256, 0, stream>>>(pSims, lab, supL, pMet, b_met, W_con,
                                               pCon, out_fsp);
    combine     <<<128,      256, 0, stream>>>(pSim, b_sim, pDiv, b_div, pCon, b_con,
                                               out_sim, out_div, out_con);
}